// Round 13
// baseline (222.398 us; speedup 1.0000x reference)
//
#include <hip/hip_runtime.h>
#include <hip/hip_bf16.h>

typedef __hip_bfloat16 bf16;
typedef __bf16 bfv8 __attribute__((ext_vector_type(8)));
typedef float fv4 __attribute__((ext_vector_type(4)));

__device__ __forceinline__ float bf2f(bf16 x){ return __bfloat162float(x); }
__device__ __forceinline__ bf16 f2bf(float x){ return __float2bfloat16(x); }
__device__ __forceinline__ float blo(unsigned u){ return __uint_as_float(u<<16); }
__device__ __forceinline__ float bhi(unsigned u){ return __uint_as_float(u & 0xffff0000u); }
struct __align__(8) bf4v { bf16 x,y,z,w; };
struct __align__(16) bf8s { ushort u[8]; };
__device__ __forceinline__ float4 ldb4(const bf16* p){
  ushort4 u = *(const ushort4*)p;
  float4 r;
  r.x = __uint_as_float(((unsigned)u.x)<<16);
  r.y = __uint_as_float(((unsigned)u.y)<<16);
  r.z = __uint_as_float(((unsigned)u.z)<<16);
  r.w = __uint_as_float(((unsigned)u.w)<<16);
  return r;
}
__device__ __forceinline__ void stb4(bf16* p, float4 v){
  bf4v t; t.x=f2bf(v.x); t.y=f2bf(v.y); t.z=f2bf(v.z); t.w=f2bf(v.w);
  *(bf4v*)p = t;
}

#define L_SEQ 2048
#define DPROJ 2568
#define NCHUNK 16
#define TCH 128

// ---------------- prep: castU + transpose W_in/W_out/W_ydown, one dispatch ----------------
__device__ __forceinline__ void tbody(const float* __restrict__ in, bf16* __restrict__ out,
                                      int R, int C, int Cpad, int bx, int by, float (*t)[33])
{
  int c0 = bx*32, r0 = by*32;
  int tx = threadIdx.x & 31, ty = threadIdx.x >> 5;
  for (int i=0;i<32;i+=8){
    int r = r0+i+ty, cc = c0+tx;
    t[i+ty][tx] = (r<R && cc<C) ? in[(size_t)r*C+cc] : 0.f;
  }
  __syncthreads();
  for (int i=0;i<32;i+=8){
    int cc = c0+i+ty, r = r0+tx;
    if (cc<Cpad && r<R) out[(size_t)cc*R + r] = f2bf(t[tx][i+ty]);
  }
}

__global__ void prep(const float* __restrict__ u, bf16* __restrict__ ubf,
                     const float* __restrict__ Win, bf16* __restrict__ WinT,
                     const float* __restrict__ Wout, bf16* __restrict__ WoutT,
                     const float* __restrict__ Wyd, bf16* __restrict__ WydT)
{
  __shared__ float t[32][33];
  int b = blockIdx.x;
  if (b < 1024){
    int i = (b*256 + threadIdx.x)*4;
    float4 v = *(const float4*)&u[i];
    stb4(&ubf[i], v);
  } else if (b < 2368){
    int idx = b - 1024;
    tbody(Win, WinT, 512, DPROJ, 2688, idx%84, idx/84, t);
  } else if (b < 2880){
    int idx = b - 2368;
    tbody(Wout, WoutT, 1024, 512, 512, idx%16, idx/16, t);
  } else {
    int idx = b - 2880;
    tbody(Wyd, WydT, 128, 64, 64, idx%2, idx/2, t);
  }
}

// ------- GEMM1 (MFMA, 128x128 tile): proj = ubf @ W_in + b_in; side fp32 for dt/lam cols -------
__global__ void __launch_bounds__(256) gemm1_mfma(const bf16* __restrict__ A, const bf16* __restrict__ BT,
                                                  const float* __restrict__ bias, bf16* __restrict__ C,
                                                  float* __restrict__ side)
{
  const int K = 512;
  __shared__ __align__(16) bf16 As[128*40];
  __shared__ __align__(16) bf16 Bs[128*40];
  int tid = threadIdx.x;
  int col0 = blockIdx.x*128, row0 = blockIdx.y*128;
  int wid = tid>>6, lane = tid&63;
  int wm = (wid&1)*64, wn = (wid>>1)*64;
  int lm = lane&15, lq = lane>>4;
  fv4 acc[4][4] = {};
  for (int k0=0;k0<K;k0+=32){
    #pragma unroll
    for (int i=0;i<2;i++){
      int e = tid + i*256;
      int r = e>>2, k8 = (e&3)*8;
      *(bf8s*)&As[r*40+k8] = *(const bf8s*)&A[(size_t)(row0+r)*K + k0 + k8];
      *(bf8s*)&Bs[r*40+k8] = *(const bf8s*)&BT[(size_t)(col0+r)*K + k0 + k8];
    }
    __syncthreads();
    bfv8 af[4], bfr[4];
    #pragma unroll
    for (int mf=0;mf<4;mf++) af[mf] = *(const bfv8*)&As[(wm+mf*16+lm)*40 + lq*8];
    #pragma unroll
    for (int nf=0;nf<4;nf++) bfr[nf] = *(const bfv8*)&Bs[(wn+nf*16+lm)*40 + lq*8];
    #pragma unroll
    for (int mf=0;mf<4;mf++)
      #pragma unroll
      for (int nf=0;nf<4;nf++)
        acc[mf][nf] = __builtin_amdgcn_mfma_f32_16x16x32_bf16(af[mf], bfr[nf], acc[mf][nf], 0,0,0);
    __syncthreads();
  }
  #pragma unroll
  for (int mf=0;mf<4;mf++){
    #pragma unroll
    for (int nf=0;nf<4;nf++){
      int gcol = col0 + wn + nf*16 + lm;
      if (gcol < DPROJ){
        float bia = bias[gcol];
        #pragma unroll
        for (int r=0;r<4;r++){
          int grow = row0 + wm + mf*16 + lq*4 + r;
          float v = acc[mf][nf][r] + bia;
          C[(size_t)grow*DPROJ + gcol] = f2bf(v);
          if (gcol >= 2560) side[grow*8 + (gcol-2560)] = v;
        }
      }
    }
  }
}

// ---------------- GEMM_OUT (MFMA, BK=32 — R11-verified): out = y2 @ W_out ----------------
__global__ void __launch_bounds__(256) gemmo_mfma(const bf16* __restrict__ Yp, const bf16* __restrict__ BT,
                                                  float* __restrict__ C)
{
  const int K = 1024;
  __shared__ __align__(16) bf16 As[64*40];
  __shared__ __align__(16) bf16 Bs[64*40];
  int tid = threadIdx.x;
  int col0 = blockIdx.x*64, row0 = blockIdx.y*64;
  int wid = tid>>6, lane = tid&63;
  int wm = (wid&1)*32, wn = (wid>>1)*32;
  int lm = lane&15, lq = lane>>4;
  fv4 acc[2][2] = {};
  for (int k0=0;k0<K;k0+=32){
    {
      int m = tid>>2, k8 = (tid&3)*8;
      int kg = k0 + k8;
      *(bf8s*)&As[m*40+k8] = *(const bf8s*)&Yp[(size_t)(row0+m)*2048 + ((kg>>6)*128) + 64 + (kg&63)];
    }
    {
      int n = tid>>2, k8 = (tid&3)*8;
      *(bf8s*)&Bs[n*40+k8] = *(const bf8s*)&BT[(size_t)(col0+n)*K + k0 + k8];
    }
    __syncthreads();
    bfv8 af[2], bfr[2];
    #pragma unroll
    for (int mf=0;mf<2;mf++) af[mf] = *(const bfv8*)&As[(wm+mf*16+lm)*40 + lq*8];
    #pragma unroll
    for (int nf=0;nf<2;nf++) bfr[nf] = *(const bfv8*)&Bs[(wn+nf*16+lm)*40 + lq*8];
    #pragma unroll
    for (int mf=0;mf<2;mf++)
      #pragma unroll
      for (int nf=0;nf<2;nf++)
        acc[mf][nf] = __builtin_amdgcn_mfma_f32_16x16x32_bf16(af[mf], bfr[nf], acc[mf][nf], 0,0,0);
    __syncthreads();
  }
  #pragma unroll
  for (int mf=0;mf<2;mf++)
    #pragma unroll
    for (int nf=0;nf<2;nf++){
      int gcol = col0 + wn + nf*16 + lm;
      #pragma unroll
      for (int r=0;r<4;r++){
        int grow = row0 + wm + mf*16 + lq*4 + r;
        C[(size_t)grow*512 + gcol] = acc[mf][nf][r];
      }
    }
}

// ------- K23M: one dispatch. Block 0: csdt cumsum (for k45). Blocks 1..64: per-(c,g) coefs -----
__global__ void k23m(const float* __restrict__ dlraw, const float* __restrict__ A_log,
                     float* __restrict__ csdt,
                     float* __restrict__ u1b, float* __restrict__ u12b,
                     float* __restrict__ vsb, float* __restrict__ vfinb,
                     float* __restrict__ dcg, float* __restrict__ csb)
{
  __shared__ float raw[L_SEQ*8];
  __shared__ float dts[L_SEQ*4];
  __shared__ float segs[4][64];
  __shared__ float dt_l[129], lam_l[129], cs_l[128];
  int tid = threadIdx.x;
  if (blockIdx.x == 0){
    for (int e=tid;e<L_SEQ*8;e+=256) raw[e] = dlraw[e];
    __syncthreads();
    int g = tid & 3, seg = tid >> 2;
    for (int i = 0; i < 32; i++){
      int l = seg*32 + i;
      float dr = raw[l*8 + g];
      float dt = (dr > 15.f) ? dr : log1pf(__expf(dr));
      dts[l*4+g] = dt;
    }
    __syncthreads();
    float s = 0.f;
    for (int i=0;i<32;i++) s += dts[(seg*32+i)*4 + g];
    segs[g][seg] = s;
    __syncthreads();
    if (tid < 4) { float run = 0.f; for (int q=0;q<64;q++){ float t = segs[tid][q]; segs[tid][q] = run; run += t; } }
    __syncthreads();
    float run = segs[g][seg];
    for (int i=0;i<32;i++){ int l = seg*32+i; run += dts[l*4+g]; csdt[l*4+g] = run; }
  } else {
    int idx0 = blockIdx.x - 1;
    int c = idx0 >> 2, g = idx0 & 3;
    int l0 = c*TCH;
    float Ah = -__expf(A_log[g]);
    if (tid < 129){
      int l = l0 - 1 + tid;
      if (l >= 0){
        float dr = dlraw[l*8 + g];
        float lr = dlraw[l*8 + 4 + g];
        dt_l[tid]  = (dr > 15.f) ? dr : log1pf(__expf(dr));
        lam_l[tid] = 1.f/(1.f+__expf(-lr));
      } else { dt_l[tid] = 0.f; lam_l[tid] = 0.f; }
    }
    __syncthreads();
    if (tid < 128) cs_l[tid] = dt_l[tid+1]*Ah;
    __syncthreads();
    for (int off=1; off<128; off<<=1){
      float add = 0.f;
      if (tid<128 && tid>=off) add = cs_l[tid-off];
      __syncthreads();
      if (tid<128) cs_l[tid] += add;
      __syncthreads();
    }
    if (tid == 0) dcg[c*4+g] = __expf(cs_l[127]);
    if (tid < 128) csb[(c*4+g)*128 + tid] = cs_l[tid];
    __syncthreads();
    int q = tid>>6, ln = tid&63;
    int base = ((c*4+g)*4+q)*160;
    float ref = cs_l[q*32+16];
    for (int jj = ln; jj < 160; jj += 64){
      float u1v = 0.f, u2v = 0.f;
      if (jj>=1 && jj<=128) u1v = lam_l[jj]*dt_l[jj]*__expf(fminf(ref-cs_l[jj-1],60.f));
      if (jj<=127) u2v = (1.f-lam_l[jj+1])*dt_l[jj]*__expf(fminf(ref-cs_l[jj],60.f));
      u1b[base+jj] = u1v;
      u12b[base+jj] = u1v + u2v;
    }
    if (ln < 32) vsb[((c*4+g)*4+q)*32 + ln] = __expf(fminf(cs_l[q*32+ln]-ref,60.f));
    if (ln == 0) vfinb[(c*4+g)*4+q] = __expf(fminf(cs_l[127]-ref,60.f));
  }
}

// ------- K45: fused rmsnorm+RoPE and x_up per l ----------------
__global__ void __launch_bounds__(256) k45(
  const bf16* __restrict__ proj, const float* __restrict__ wB, const float* __restrict__ wC,
  const float* __restrict__ biasB, const float* __restrict__ biasC,
  const float* __restrict__ theta_log, const float* __restrict__ csdt,
  const float* __restrict__ Wx,
  bf16* __restrict__ Br, bf16* __restrict__ Cr, bf16* __restrict__ xup)
{
  __shared__ __align__(16) float wsm[64*128];
  __shared__ float xs[1024];
  int l = blockIdx.x, tid = threadIdx.x;
  const bf16* pr = proj + (size_t)l*DPROJ;
  for (int e=tid;e<8192;e+=256) wsm[e] = Wx[e];
  for (int e=tid;e<1024;e+=256){ float v = bf2f(pr[1024+e]); xs[e] = v/(1.f+__expf(-v)); }
  {
    int g = tid >> 6, idx = tid & 63;
    float bv = bf2f(pr[2048 + g*64 + idx]);
    float cv = bf2f(pr[2304 + g*64 + idx]);
    float sb = bv*bv, sc = cv*cv;
    #pragma unroll
    for (int off=32; off; off>>=1){ sb += __shfl_xor(sb, off); sc += __shfl_xor(sc, off); }
    float rb = rsqrtf(sb*(1.f/64.f) + 1e-5f);
    float rc = rsqrtf(sc*(1.f/64.f) + 1e-5f);
    float bm = bv*rb*wB[idx] + biasB[g*64+idx];
    float cm = cv*rc*wC[idx] + biasC[g*64+idx];
    int k = idx >> 2;
    float ang = csdt[l*4+g] * __expf(theta_log[g*16+k]);
    float ca = cosf(ang), sa = sinf(ang);
    float bp = __shfl_xor(bm, 2);
    float cp = __shfl_xor(cm, 2);
    bool is_im = (idx >> 1) & 1;
    float bo = is_im ? (bp*sa + bm*ca) : (bm*ca - bp*sa);
    float co = is_im ? (cp*sa + cm*ca) : (cm*ca - cp*sa);
    Br[((size_t)l*4+g)*64 + idx] = f2bf(bo);
    Cr[((size_t)l*4+g)*64 + idx] = f2bf(co);
  }
  __syncthreads();
  {
    int h = tid>>4, prb = (tid&15)*8;
    float acc[8] = {};
    for (int k=0;k<64;k++){
      float xv = xs[h*64+k];
      const float4* w4 = (const float4*)&wsm[k*128 + prb];
      float4 a = w4[0], b = w4[1];
      acc[0]+=xv*a.x; acc[1]+=xv*a.y; acc[2]+=xv*a.z; acc[3]+=xv*a.w;
      acc[4]+=xv*b.x; acc[5]+=xv*b.y; acc[6]+=xv*b.z; acc[7]+=xv*b.w;
    }
    bf16* o = xup + ((size_t)l*16+h)*128 + prb;
    stb4(o,   make_float4(acc[0],acc[1],acc[2],acc[3]));
    stb4(o+4, make_float4(acc[4],acc[5],acc[6],acc[7]));
  }
}

// ------- K6Y (MFMA): y_diag per (chunk, group, t-quarter, head); q==3 also emits h_final --------
__global__ void __launch_bounds__(256) k6y(
  const bf16* __restrict__ Br, const bf16* __restrict__ Cr, const bf16* __restrict__ xup,
  const float* __restrict__ u1b, const float* __restrict__ u12b,
  const float* __restrict__ vsb, const float* __restrict__ vfinb,
  bf16* __restrict__ ypr, bf16* __restrict__ hfin)
{
  __shared__ __align__(16) bf16 Cs[64*40];
  __shared__ __align__(16) bf16 Bs[64*40];
  __shared__ __align__(16) bf16 Bsn[32*72];
  __shared__ __align__(16) bf16 Fs[64*72];
  __shared__ __align__(16) bf16 Xs[64*72];
  __shared__ float u1s[160], u12s[160], vs_[32];
  int bx = blockIdx.x; int g = bx & 3, q = bx >> 2;
  int c = blockIdx.y;
  int h4 = blockIdx.z;
  int h = g*4 + h4;
  int tid = threadIdx.x;
  int l0 = c*TCH;
  int w = tid>>6, lane = tid&63, lm = lane&15, lq = lane>>4;
  int idx = ((c*4+g)*4+q);
  if (tid < 160){ u1s[tid] = u1b[idx*160+tid]; u12s[tid] = u12b[idx*160+tid]; }
  if (tid < 32) vs_[tid] = vsb[idx*32+tid];
  float vfin = vfinb[idx];
  for (int e4 = tid; e4 < 512; e4 += 256){
    int tl = e4>>4, c4 = (e4&15)*4;
    bf4v v = *(const bf4v*)&Cr[((size_t)(l0+q*32+tl)*4+g)*64 + c4];
    bf16 arr[4] = {v.x,v.y,v.z,v.w};
    #pragma unroll
    for (int i=0;i<4;i++){ int q6=c4+i; Cs[((tl<<1)|(q6&1))*40 + (q6>>1)] = arr[i]; }
  }
  __syncthreads();
  fv4 acc[4] = {};
  fv4 acch[2] = {};
  int nch = (q+2 < 5) ? (q+2) : 5;
  for (int kc=0; kc<nch; kc++){
    for (int e4 = tid; e4 < 512; e4 += 256){
      int jjloc = e4>>4, c4 = (e4&15)*4;
      int jj = kc*32 + jjloc; int l = l0-1+jj;
      bf4v v;
      if (l >= 0 && jj <= 128) v = *(const bf4v*)&Br[((size_t)l*4+g)*64 + c4];
      else { v.x=v.y=v.z=v.w = f2bf(0.f); }
      bf16 arr[4] = {v.x,v.y,v.z,v.w};
      #pragma unroll
      for (int i=0;i<4;i++){ int q6=c4+i; Bs[((q6&1)*32+jjloc)*40 + (q6>>1)] = arr[i]; }
      if (q == 3){
        float gcv = vfin * u12s[jj];
        #pragma unroll
        for (int i=0;i<4;i++){ int q6=c4+i; Bsn[(q6>>1)*72 + (q6&1)*32 + jjloc] = f2bf(gcv*bf2f(arr[i])); }
      }
    }
    for (int e4 = tid; e4 < 1024; e4 += 256){
      int jjloc = e4>>5, c4 = (e4&31)*4;
      int jj = kc*32+jjloc; int l = l0-1+jj;
      bf4v v;
      if (l>=0 && jj<=128) v = *(const bf4v*)&xup[((size_t)l*16 + h)*128 + c4];
      else { v.x=v.y=v.z=v.w = f2bf(0.f); }
      bf16 arr[4] = {v.x,v.y,v.z,v.w};
      #pragma unroll
      for (int i=0;i<4;i++){ int q7=c4+i; Xs[(q7>>1)*72 + (q7&1)*32 + jjloc] = arr[i]; }
    }
    __syncthreads();
    {
      bfv8 a = *(const bfv8*)&Cs[(w*16+lm)*40 + lq*8];
      fv4 zz = {0.f,0.f,0.f,0.f};
      int rb = w*16 + lq*4;
      float vA = vs_[rb>>1];
      float vB = vs_[(rb>>1)+1];
      #pragma unroll
      for (int nt=0;nt<4;nt++){
        bfv8 b = *(const bfv8*)&Bs[(nt*16+lm)*40 + lq*8];
        fv4 s = __builtin_amdgcn_mfma_f32_16x16x32_bf16(a, b, zz, 0,0,0);
        int col = nt*16+lm;
        int jj = kc*32 + (col&31);
        float u1v = u1s[jj], u12v = u12s[jj];
        #pragma unroll
        for (int r=0;r<4;r++){
          int row = rb + r;
          float vT = (r<2) ? vA : vB;
          float cf;
          if (kc < q) cf = u12v;
          else {
            int T = q*32 + (row>>1);
            if (kc == q) cf = (jj<=T) ? u12v : ((jj==T+1) ? u1v : 0.f);
            else         cf = (jj==T+1) ? u1v : 0.f;
          }
          Fs[row*72+col] = f2bf(cf*vT*s[r]);
        }
      }
    }
    __syncthreads();
    #pragma unroll
    for (int r2=0;r2<2;r2++){
      bfv8 a = *(const bfv8*)&Fs[(w*16+lm)*72 + r2*32 + lq*8];
      #pragma unroll
      for (int nt=0;nt<4;nt++){
        bfv8 b = *(const bfv8*)&Xs[(nt*16+lm)*72 + r2*32 + lq*8];
        acc[nt] = __builtin_amdgcn_mfma_f32_16x16x32_bf16(a, b, acc[nt], 0,0,0);
      }
    }
    if (q == 3){
      #pragma unroll
      for (int r2=0;r2<2;r2++){
        bfv8 a = *(const bfv8*)&Xs[(w*16+lm)*72 + r2*32 + lq*8];
        #pragma unroll
        for (int nt2=0;nt2<2;nt2++){
          bfv8 b = *(const bfv8*)&Bsn[(nt2*16+lm)*72 + r2*32 + lq*8];
          acch[nt2] = __builtin_amdgcn_mfma_f32_16x16x32_bf16(a, b, acch[nt2], 0,0,0);
        }
      }
    }
    __syncthreads();
  }
  #pragma unroll
  for (int nt=0;nt<4;nt++){
    int p = nt*16+lm;
    #pragma unroll
    for (int r=0;r<4;r++){
      int row = w*16+lq*4+r;
      int T = q*32+(row>>1), r1 = row&1;
      ypr[((size_t)(l0+T)*16 + h)*128 + p*2+r1] = f2bf(acc[nt][r]);
    }
  }
  if (q == 3){
    #pragma unroll
    for (int nt2=0;nt2<2;nt2++){
      int n = nt2*16+lm;
      #pragma unroll
      for (int r=0;r<4;r++){
        int p = w*16+lq*4+r;
        hfin[(((size_t)c*16+h)*64 + p)*32 + n] = f2bf(acch[nt2][r]);
      }
    }
  }
}

// ------- K8AF: fused inter-chunk scan + y_off (MFMA) + ydown (MFMA) + gates, per (c,h) ---------
__global__ void __launch_bounds__(256) k8af(
  const bf16* __restrict__ Cr, const bf16* __restrict__ hfin,
  const float* __restrict__ dcg, const float* __restrict__ csb,
  bf16* __restrict__ ypr, const bf16* __restrict__ WydT,
  const bf16* __restrict__ proj, const float* __restrict__ Dp)
{
  __shared__ __align__(16) char arena[52224];
  bf16* C2s = (bf16*)arena;              // [256*40] 20480 B (phase 1)
  bf16* hT  = (bf16*)(arena + 20480);    // [64*40]   5120 B (phase 1)
  float* cse = (float*)(arena + 25600);  // [128]      512 B (phase 1)
  bf16* Yf  = (bf16*)arena;              // [128*136] 34816 B (phase 2, aliases C2s/hT/cse)
  bf16* Wds = (bf16*)(arena + 34816);    // [64*136] 17408 B (both phases)
  int h = blockIdx.x, c = blockIdx.y;
  int g = h >> 2;
  int tid = threadIdx.x;
  int l0 = c*TCH;
  int w = tid>>6, lane = tid&63, lm = lane&15, lq = lane>>4;
  for (int e4 = tid; e4 < 2048; e4 += 256){
    int tl = e4>>4, c4 = (e4&15)*4;
    bf4v v = *(const bf4v*)&Cr[((size_t)(l0+tl)*4+g)*64 + c4];
    bf16 arr[4] = {v.x,v.y,v.z,v.w};
    #pragma unroll
    for (int i=0;i<4;i++){ int q6=c4+i; C2s[((tl<<1)|(q6&1))*40 + (q6>>1)] = arr[i]; }
  }
  for (int e = tid; e < 1024; e += 256){
    int qq = e>>4, k8 = (e&15)*8;
    *(bf8s*)&Wds[qq*136 + k8] = *(const bf8s*)&WydT[qq*128 + k8];
  }
  {
    int e0 = tid*8;
    float carry[8] = {};
    for (int j = 0; j < c; j++){
      float dc = dcg[j*4+g];
      float4 a = ldb4(&hfin[((size_t)j*16+h)*2048 + e0]);
      float4 b = ldb4(&hfin[((size_t)j*16+h)*2048 + e0 + 4]);
      carry[0]=carry[0]*dc+a.x; carry[1]=carry[1]*dc+a.y; carry[2]=carry[2]*dc+a.z; carry[3]=carry[3]*dc+a.w;
      carry[4]=carry[4]*dc+b.x; carry[5]=carry[5]*dc+b.y; carry[6]=carry[6]*dc+b.z; carry[7]=carry[7]*dc+b.w;
    }
    int p = e0>>5, n = e0&31;
    stb4(&hT[p*40+n],   make_float4(carry[0],carry[1],carry[2],carry[3]));
    stb4(&hT[p*40+n+4], make_float4(carry[4],carry[5],carry[6],carry[7]));
  }
  if (tid < 128) cse[tid] = __expf(csb[(c*4+g)*128 + tid]);
  __syncthreads();
  float yfull[4][4][4];
  fv4 zz = {0.f,0.f,0.f,0.f};
  #pragma unroll
  for (int mi=0;mi<4;mi++){
    int mt = w*4 + mi;
    bfv8 a = *(const bfv8*)&C2s[(mt*16+lm)*40 + lq*8];
    #pragma unroll
    for (int nt=0;nt<4;nt++){
      bfv8 b = *(const bfv8*)&hT[(nt*16+lm)*40 + lq*8];
      fv4 s = __builtin_amdgcn_mfma_f32_16x16x32_bf16(a, b, zz, 0,0,0);
      int p = nt*16+lm;
      #pragma unroll
      for (int r=0;r<4;r++){
        int row = mt*16+lq*4+r;
        int tl = row>>1, r1 = row&1;
        float yd = bf2f(ypr[((size_t)(l0+tl)*16 + h)*128 + p*2 + r1]);
        yfull[mi][nt][r] = yd + cse[tl]*s[r];
      }
    }
  }
  __syncthreads();
  #pragma unroll
  for (int mi=0;mi<4;mi++){
    int mt = w*4 + mi;
    #pragma unroll
    for (int nt=0;nt<4;nt++){
      int p = nt*16+lm;
      #pragma unroll
      for (int r=0;r<4;r++){
        int row = mt*16+lq*4+r;
        int tl = row>>1, r1 = row&1;
        Yf[tl*136 + p*2 + r1] = f2bf(yfull[mi][nt][r]);
      }
    }
  }
  __syncthreads();
  fv4 acc2[2][4] = {};
  #pragma unroll
  for (int kq=0;kq<4;kq++){
    #pragma unroll
    for (int m2=0;m2<2;m2++){
      bfv8 a = *(const bfv8*)&Yf[((w*2+m2)*16+lm)*136 + kq*32 + lq*8];
      #pragma unroll
      for (int nt2=0;nt2<4;nt2++){
        bfv8 b = *(const bfv8*)&Wds[(nt2*16+lm)*136 + kq*32 + lq*8];
        acc2[m2][nt2] = __builtin_amdgcn_mfma_f32_16x16x32_bf16(a, b, acc2[m2][nt2], 0,0,0);
      }
    }
  }
  float dv = Dp[h];
  #pragma unroll
  for (int m2=0;m2<2;m2++){
    #pragma unroll
    for (int nt2=0;nt2<4;nt2++){
      int qq = nt2*16+lm;
      #pragma unroll
      for (int r=0;r<4;r++){
        int tl = (w*2+m2)*16 + lq*4 + r;
        size_t lrow = (size_t)(l0+tl)*DPROJ;
        float x = bf2f(proj[lrow + 1024 + h*64 + qq]);
        float z = bf2f(proj[lrow + h*64 + qq]);
        float xs = x/(1.f+__expf(-x));
        float zs = z/(1.f+__expf(-z));
        float outv = (acc2[m2][nt2][r] + dv*xs)*zs;
        ypr[((size_t)(l0+tl)*16 + h)*128 + 64 + qq] = f2bf(outv);
      }
    }
  }
}

extern "C" void kernel_launch(void* const* d_in, const int* in_sizes, int n_in,
                              void* d_out, int out_size, void* d_ws, size_t ws_size,
                              hipStream_t stream) {
  const float* u       = (const float*)d_in[0];
  const float* W_in    = (const float*)d_in[1];
  const float* b_in    = (const float*)d_in[2];
  const float* W_xup   = (const float*)d_in[3];
  const float* W_ydown = (const float*)d_in[4];
  const float* A_log   = (const float*)d_in[5];
  const float* theta_l = (const float*)d_in[6];
  const float* D_p     = (const float*)d_in[7];
  const float* wB      = (const float*)d_in[8];
  const float* wC      = (const float*)d_in[9];
  const float* biasB   = (const float*)d_in[10];
  const float* biasC   = (const float*)d_in[11];
  const float* W_out   = (const float*)d_in[12];
  float* out = (float*)d_out;

  char* w = (char*)d_ws;
  bf16*  proj  = (bf16*)(w);                       // 10,518,528 B
  float* dlraw = (float*)(w + 10518528);           //     65,536 B
  float* csdt  = (float*)(w + 10649600);           //     32,768 B
  bf16*  Brb   = (bf16*)(w + 10682368);            //  1,048,576 B
  bf16*  Crb   = (bf16*)(w + 11730944);            //  1,048,576 B
  bf16*  xupb  = (bf16*)(w + 12779520);            //  8,388,608 B
  bf16*  hfin  = (bf16*)(w + 21168128);            //  1,048,576 B
  float* csb   = (float*)(w + 23266304);           //     32,768 B
  bf16*  ypr   = (bf16*)(w + 23299072);            //  8,388,608 B
  bf16*  WinT  = (bf16*)(w + 23299072);            //  aliased over ypr (dead once k6y writes ypr)
  bf16*  ubf   = (bf16*)(w + 31687680);            //  2,097,152 B
  bf16*  WoutT = (bf16*)(w + 33784832);            //  1,048,576 B
  bf16*  WydT  = (bf16*)(w + 34833408);            //     16,384 B
  float* u1b   = (float*)(w + 34849792);           //    163,840 B
  float* u12b  = (float*)(w + 35013632);           //    163,840 B
  float* vsb   = (float*)(w + 35177472);           //     32,768 B
  float* vfinb = (float*)(w + 35210240);           //      1,024 B
  float* dcg   = (float*)(w + 35211264);           //        256 B

  prep<<<2888,256,0,stream>>>(u, ubf, W_in, WinT, W_out, WoutT, W_ydown, WydT);
  gemm1_mfma<<<dim3(21,16),256,0,stream>>>(ubf, WinT, b_in, proj, dlraw);
  k23m<<<65,256,0,stream>>>(dlraw, A_log, csdt, u1b, u12b, vsb, vfinb, dcg, csb);
  k45<<<2048,256,0,stream>>>(proj, wB, wC, biasB, biasC, theta_l, csdt, W_xup, Brb, Crb, xupb);
  k6y<<<dim3(16,16,4),256,0,stream>>>(Brb, Crb, xupb, u1b, u12b, vsb, vfinb, ypr, hfin);
  k8af<<<dim3(16,16),256,0,stream>>>(Crb, hfin, dcg, csb, ypr, WydT, proj, D_p);
  gemmo_mfma<<<dim3(8,32),256,0,stream>>>(ypr, WoutT, out);
}

// Round 14
// 204.748 us; speedup vs baseline: 1.0862x; 1.0862x over previous
//
#include <hip/hip_runtime.h>
#include <hip/hip_bf16.h>

typedef __hip_bfloat16 bf16;
typedef __bf16 bfv8 __attribute__((ext_vector_type(8)));
typedef float fv4 __attribute__((ext_vector_type(4)));

__device__ __forceinline__ float bf2f(bf16 x){ return __bfloat162float(x); }
__device__ __forceinline__ bf16 f2bf(float x){ return __float2bfloat16(x); }
__device__ __forceinline__ float blo(unsigned u){ return __uint_as_float(u<<16); }
__device__ __forceinline__ float bhi(unsigned u){ return __uint_as_float(u & 0xffff0000u); }
struct __align__(8) bf4v { bf16 x,y,z,w; };
struct __align__(16) bf8s { ushort u[8]; };
__device__ __forceinline__ float4 ldb4(const bf16* p){
  ushort4 u = *(const ushort4*)p;
  float4 r;
  r.x = __uint_as_float(((unsigned)u.x)<<16);
  r.y = __uint_as_float(((unsigned)u.y)<<16);
  r.z = __uint_as_float(((unsigned)u.z)<<16);
  r.w = __uint_as_float(((unsigned)u.w)<<16);
  return r;
}
__device__ __forceinline__ void stb4(bf16* p, float4 v){
  bf4v t; t.x=f2bf(v.x); t.y=f2bf(v.y); t.z=f2bf(v.z); t.w=f2bf(v.w);
  *(bf4v*)p = t;
}

#define L_SEQ 2048
#define DPROJ 2568
#define NCHUNK 16
#define TCH 128

// ---------------- prep: castU + transpose W_in/W_out/W_ydown, one dispatch ----------------
__device__ __forceinline__ void tbody(const float* __restrict__ in, bf16* __restrict__ out,
                                      int R, int C, int Cpad, int bx, int by, float (*t)[33])
{
  int c0 = bx*32, r0 = by*32;
  int tx = threadIdx.x & 31, ty = threadIdx.x >> 5;
  for (int i=0;i<32;i+=8){
    int r = r0+i+ty, cc = c0+tx;
    t[i+ty][tx] = (r<R && cc<C) ? in[(size_t)r*C+cc] : 0.f;
  }
  __syncthreads();
  for (int i=0;i<32;i+=8){
    int cc = c0+i+ty, r = r0+tx;
    if (cc<Cpad && r<R) out[(size_t)cc*R + r] = f2bf(t[tx][i+ty]);
  }
}

__global__ void prep(const float* __restrict__ u, bf16* __restrict__ ubf,
                     const float* __restrict__ Win, bf16* __restrict__ WinT,
                     const float* __restrict__ Wout, bf16* __restrict__ WoutT,
                     const float* __restrict__ Wyd, bf16* __restrict__ WydT)
{
  __shared__ float t[32][33];
  int b = blockIdx.x;
  if (b < 1024){
    int i = (b*256 + threadIdx.x)*4;
    float4 v = *(const float4*)&u[i];
    stb4(&ubf[i], v);
  } else if (b < 2368){
    int idx = b - 1024;
    tbody(Win, WinT, 512, DPROJ, 2688, idx%84, idx/84, t);
  } else if (b < 2880){
    int idx = b - 2368;
    tbody(Wout, WoutT, 1024, 512, 512, idx%16, idx/16, t);
  } else {
    int idx = b - 2880;
    tbody(Wyd, WydT, 128, 64, 64, idx%2, idx/2, t);
  }
}

// ------- GEMM1 (MFMA, 128x128 tile): proj = ubf @ W_in + b_in; side fp32 for dt/lam cols -------
__global__ void __launch_bounds__(256) gemm1_mfma(const bf16* __restrict__ A, const bf16* __restrict__ BT,
                                                  const float* __restrict__ bias, bf16* __restrict__ C,
                                                  float* __restrict__ side)
{
  const int K = 512;
  __shared__ __align__(16) bf16 As[128*40];
  __shared__ __align__(16) bf16 Bs[128*40];
  int tid = threadIdx.x;
  int col0 = blockIdx.x*128, row0 = blockIdx.y*128;
  int wid = tid>>6, lane = tid&63;
  int wm = (wid&1)*64, wn = (wid>>1)*64;
  int lm = lane&15, lq = lane>>4;
  fv4 acc[4][4] = {};
  for (int k0=0;k0<K;k0+=32){
    #pragma unroll
    for (int i=0;i<2;i++){
      int e = tid + i*256;
      int r = e>>2, k8 = (e&3)*8;
      *(bf8s*)&As[r*40+k8] = *(const bf8s*)&A[(size_t)(row0+r)*K + k0 + k8];
      *(bf8s*)&Bs[r*40+k8] = *(const bf8s*)&BT[(size_t)(col0+r)*K + k0 + k8];
    }
    __syncthreads();
    bfv8 af[4], bfr[4];
    #pragma unroll
    for (int mf=0;mf<4;mf++) af[mf] = *(const bfv8*)&As[(wm+mf*16+lm)*40 + lq*8];
    #pragma unroll
    for (int nf=0;nf<4;nf++) bfr[nf] = *(const bfv8*)&Bs[(wn+nf*16+lm)*40 + lq*8];
    #pragma unroll
    for (int mf=0;mf<4;mf++)
      #pragma unroll
      for (int nf=0;nf<4;nf++)
        acc[mf][nf] = __builtin_amdgcn_mfma_f32_16x16x32_bf16(af[mf], bfr[nf], acc[mf][nf], 0,0,0);
    __syncthreads();
  }
  #pragma unroll
  for (int mf=0;mf<4;mf++){
    #pragma unroll
    for (int nf=0;nf<4;nf++){
      int gcol = col0 + wn + nf*16 + lm;
      if (gcol < DPROJ){
        float bia = bias[gcol];
        #pragma unroll
        for (int r=0;r<4;r++){
          int grow = row0 + wm + mf*16 + lq*4 + r;
          float v = acc[mf][nf][r] + bia;
          C[(size_t)grow*DPROJ + gcol] = f2bf(v);
          if (gcol >= 2560) side[grow*8 + (gcol-2560)] = v;
        }
      }
    }
  }
}

// ---------------- GEMM_OUT (MFMA): out(2048x512 fp32) = y2(interleaved ypr bf16) @ W_out --------
__global__ void __launch_bounds__(256) gemmo_mfma(const bf16* __restrict__ Yp, const bf16* __restrict__ BT,
                                                  float* __restrict__ C)
{
  const int K = 1024;
  __shared__ __align__(16) bf16 As[64*40];
  __shared__ __align__(16) bf16 Bs[64*40];
  int tid = threadIdx.x;
  int col0 = blockIdx.x*64, row0 = blockIdx.y*64;
  int wid = tid>>6, lane = tid&63;
  int wm = (wid&1)*32, wn = (wid>>1)*32;
  int lm = lane&15, lq = lane>>4;
  fv4 acc[2][2] = {};
  for (int k0=0;k0<K;k0+=32){
    {
      int m = tid>>2, k8 = (tid&3)*8;
      int kg = k0 + k8;
      *(bf8s*)&As[m*40+k8] = *(const bf8s*)&Yp[(size_t)(row0+m)*2048 + ((kg>>6)*128) + 64 + (kg&63)];
    }
    {
      int n = tid>>2, k8 = (tid&3)*8;
      *(bf8s*)&Bs[n*40+k8] = *(const bf8s*)&BT[(size_t)(col0+n)*K + k0 + k8];
    }
    __syncthreads();
    bfv8 af[2], bfr[2];
    #pragma unroll
    for (int mf=0;mf<2;mf++) af[mf] = *(const bfv8*)&As[(wm+mf*16+lm)*40 + lq*8];
    #pragma unroll
    for (int nf=0;nf<2;nf++) bfr[nf] = *(const bfv8*)&Bs[(wn+nf*16+lm)*40 + lq*8];
    #pragma unroll
    for (int mf=0;mf<2;mf++)
      #pragma unroll
      for (int nf=0;nf<2;nf++)
        acc[mf][nf] = __builtin_amdgcn_mfma_f32_16x16x32_bf16(af[mf], bfr[nf], acc[mf][nf], 0,0,0);
    __syncthreads();
  }
  #pragma unroll
  for (int mf=0;mf<2;mf++)
    #pragma unroll
    for (int nf=0;nf<2;nf++){
      int gcol = col0 + wn + nf*16 + lm;
      #pragma unroll
      for (int r=0;r<4;r++){
        int grow = row0 + wm + mf*16 + lq*4 + r;
        C[(size_t)grow*512 + gcol] = acc[mf][nf][r];
      }
    }
}

// ---------------- K23: dt = softplus, lam = sigmoid, csdt = cumsum_l(dt) (single block) ---------
__global__ void k23(const float* __restrict__ dlraw, float* __restrict__ dtb,
                    float* __restrict__ lamb, float* __restrict__ csdt)
{
  __shared__ float raw[L_SEQ*8];
  __shared__ float dts[L_SEQ*4];
  __shared__ float segs[4][64];
  int tid = threadIdx.x;
  for (int e=tid;e<L_SEQ*8;e+=256) raw[e] = dlraw[e];
  __syncthreads();
  int g = tid & 3, seg = tid >> 2;
  for (int i = 0; i < 32; i++){
    int l = seg*32 + i;
    float dr = raw[l*8 + g];
    float lr = raw[l*8 + 4 + g];
    float dt = (dr > 15.f) ? dr : log1pf(__expf(dr));
    dts[l*4+g] = dt;
    dtb[l*4+g] = dt;
    lamb[l*4+g] = 1.f/(1.f+__expf(-lr));
  }
  __syncthreads();
  float s = 0.f;
  for (int i=0;i<32;i++) s += dts[(seg*32+i)*4 + g];
  segs[g][seg] = s;
  __syncthreads();
  if (tid < 4) { float run = 0.f; for (int q=0;q<64;q++){ float t = segs[tid][q]; segs[tid][q] = run; run += t; } }
  __syncthreads();
  float run = segs[g][seg];
  for (int i=0;i<32;i++){ int l = seg*32+i; run += dts[l*4+g]; csdt[l*4+g] = run; }
}

// ------- K45: fused rmsnorm+RoPE and x_up per l ----------------
__global__ void __launch_bounds__(256) k45(
  const bf16* __restrict__ proj, const float* __restrict__ wB, const float* __restrict__ wC,
  const float* __restrict__ biasB, const float* __restrict__ biasC,
  const float* __restrict__ theta_log, const float* __restrict__ csdt,
  const float* __restrict__ Wx,
  bf16* __restrict__ Br, bf16* __restrict__ Cr, bf16* __restrict__ xup)
{
  __shared__ __align__(16) float wsm[64*128];
  __shared__ float xs[1024];
  int l = blockIdx.x, tid = threadIdx.x;
  const bf16* pr = proj + (size_t)l*DPROJ;
  for (int e=tid;e<8192;e+=256) wsm[e] = Wx[e];
  for (int e=tid;e<1024;e+=256){ float v = bf2f(pr[1024+e]); xs[e] = v/(1.f+__expf(-v)); }
  {
    int g = tid >> 6, idx = tid & 63;
    float bv = bf2f(pr[2048 + g*64 + idx]);
    float cv = bf2f(pr[2304 + g*64 + idx]);
    float sb = bv*bv, sc = cv*cv;
    #pragma unroll
    for (int off=32; off; off>>=1){ sb += __shfl_xor(sb, off); sc += __shfl_xor(sc, off); }
    float rb = rsqrtf(sb*(1.f/64.f) + 1e-5f);
    float rc = rsqrtf(sc*(1.f/64.f) + 1e-5f);
    float bm = bv*rb*wB[idx] + biasB[g*64+idx];
    float cm = cv*rc*wC[idx] + biasC[g*64+idx];
    int k = idx >> 2;
    float ang = csdt[l*4+g] * __expf(theta_log[g*16+k]);
    float ca = cosf(ang), sa = sinf(ang);
    float bp = __shfl_xor(bm, 2);
    float cp = __shfl_xor(cm, 2);
    bool is_im = (idx >> 1) & 1;
    float bo = is_im ? (bp*sa + bm*ca) : (bm*ca - bp*sa);
    float co = is_im ? (cp*sa + cm*ca) : (cm*ca - cp*sa);
    Br[((size_t)l*4+g)*64 + idx] = f2bf(bo);
    Cr[((size_t)l*4+g)*64 + idx] = f2bf(co);
  }
  __syncthreads();
  {
    int h = tid>>4, prb = (tid&15)*8;
    float acc[8] = {};
    for (int k=0;k<64;k++){
      float xv = xs[h*64+k];
      const float4* w4 = (const float4*)&wsm[k*128 + prb];
      float4 a = w4[0], b = w4[1];
      acc[0]+=xv*a.x; acc[1]+=xv*a.y; acc[2]+=xv*a.z; acc[3]+=xv*a.w;
      acc[4]+=xv*b.x; acc[5]+=xv*b.y; acc[6]+=xv*b.z; acc[7]+=xv*b.w;
    }
    bf16* o = xup + ((size_t)l*16+h)*128 + prb;
    stb4(o,   make_float4(acc[0],acc[1],acc[2],acc[3]));
    stb4(o+4, make_float4(acc[4],acc[5],acc[6],acc[7]));
  }
}

// ------- K6Y (MFMA): y_diag per (chunk, group, t-quarter, head); q==3 also emits h_final --------
// F-coef factorization: coef(T,jj) = v[T]*(u1[jj]*[jj<=T+1] + u2[jj]*[jj<=T]), v/u precomputed
// in-block (hidden by 1024-block occupancy — R12/R13 showed hoisting this regresses).
__global__ void __launch_bounds__(256) k6y(
  const bf16* __restrict__ Br, const bf16* __restrict__ Cr, const bf16* __restrict__ xup,
  const float* __restrict__ dtb, const float* __restrict__ lamb, const float* __restrict__ A_log,
  bf16* __restrict__ ypr, bf16* __restrict__ hfin, float* __restrict__ dcb, float* __restrict__ csb)
{
  __shared__ __align__(16) bf16 Cs[64*40];
  __shared__ __align__(16) bf16 Bs[64*40];
  __shared__ __align__(16) bf16 Bsn[32*72];
  __shared__ __align__(16) bf16 Fs[64*72];
  __shared__ __align__(16) bf16 Xs[64*72];
  __shared__ float dt_l[128], lam_l[128], cs_l[128];
  __shared__ float u1s[160], u12s[160], vs_[32];
  int bx = blockIdx.x; int g = bx & 3, q = bx >> 2;
  int c = blockIdx.y;
  int h4 = blockIdx.z;
  int h = g*4 + h4;
  int tid = threadIdx.x;
  int l0 = c*TCH;
  int w = tid>>6, lane = tid&63, lm = lane&15, lq = lane>>4;
  float Ah = -__expf(A_log[g]);
  float dt_prev = (c>0) ? dtb[(l0-1)*4+g] : 0.f;
  if (tid<128){ dt_l[tid] = dtb[(l0+tid)*4+g]; lam_l[tid] = lamb[(l0+tid)*4+g]; }
  __syncthreads();
  if (tid<128) cs_l[tid] = dt_l[tid]*Ah;
  __syncthreads();
  for (int off=1; off<128; off<<=1){
    float add = 0.f;
    if (tid<128 && tid>=off) add = cs_l[tid-off];
    __syncthreads();
    if (tid<128) cs_l[tid] += add;
    __syncthreads();
  }
  float ref = cs_l[q*32+16];
  if (tid < 160){
    int jj = tid;
    float u1v = 0.f, u2v = 0.f;
    if (jj>=1 && jj<=128) u1v = lam_l[jj-1]*dt_l[jj-1]*__expf(fminf(ref-cs_l[jj-1],60.f));
    if (jj<=127){ float dtx = (jj>=1)? dt_l[jj-1] : dt_prev; u2v = (1.f-lam_l[jj])*dtx*__expf(fminf(ref-cs_l[jj],60.f)); }
    u1s[jj] = u1v; u12s[jj] = u1v+u2v;
  }
  if (tid < 32) vs_[tid] = __expf(fminf(cs_l[q*32+tid]-ref,60.f));
  for (int e4 = tid; e4 < 512; e4 += 256){
    int tl = e4>>4, c4 = (e4&15)*4;
    bf4v v = *(const bf4v*)&Cr[((size_t)(l0+q*32+tl)*4+g)*64 + c4];
    bf16 arr[4] = {v.x,v.y,v.z,v.w};
    #pragma unroll
    for (int i=0;i<4;i++){ int q6=c4+i; Cs[((tl<<1)|(q6&1))*40 + (q6>>1)] = arr[i]; }
  }
  __syncthreads();   // covers u1s/u12s/vs_ and Cs before use
  float vfin = __expf(fminf(cs_l[127]-ref,60.f));
  fv4 acc[4] = {};
  fv4 acch[2] = {};
  int nch = (q+2 < 5) ? (q+2) : 5;
  for (int kc=0; kc<nch; kc++){
    for (int e4 = tid; e4 < 512; e4 += 256){
      int jjloc = e4>>4, c4 = (e4&15)*4;
      int jj = kc*32 + jjloc; int l = l0-1+jj;
      bf4v v;
      if (l >= 0 && jj <= 128) v = *(const bf4v*)&Br[((size_t)l*4+g)*64 + c4];
      else { v.x=v.y=v.z=v.w = f2bf(0.f); }
      bf16 arr[4] = {v.x,v.y,v.z,v.w};
      #pragma unroll
      for (int i=0;i<4;i++){ int q6=c4+i; Bs[((q6&1)*32+jjloc)*40 + (q6>>1)] = arr[i]; }
      if (q == 3){
        float gcv = vfin * u12s[jj];
        #pragma unroll
        for (int i=0;i<4;i++){ int q6=c4+i; Bsn[(q6>>1)*72 + (q6&1)*32 + jjloc] = f2bf(gcv*bf2f(arr[i])); }
      }
    }
    for (int e4 = tid; e4 < 1024; e4 += 256){
      int jjloc = e4>>5, c4 = (e4&31)*4;
      int jj = kc*32+jjloc; int l = l0-1+jj;
      bf4v v;
      if (l>=0 && jj<=128) v = *(const bf4v*)&xup[((size_t)l*16 + h)*128 + c4];
      else { v.x=v.y=v.z=v.w = f2bf(0.f); }
      bf16 arr[4] = {v.x,v.y,v.z,v.w};
      #pragma unroll
      for (int i=0;i<4;i++){ int q7=c4+i; Xs[(q7>>1)*72 + (q7&1)*32 + jjloc] = arr[i]; }
    }
    __syncthreads();
    {
      bfv8 a = *(const bfv8*)&Cs[(w*16+lm)*40 + lq*8];
      fv4 zz = {0.f,0.f,0.f,0.f};
      int rb = w*16 + lq*4;
      float vA = vs_[rb>>1];
      float vB = vs_[(rb>>1)+1];
      #pragma unroll
      for (int nt=0;nt<4;nt++){
        bfv8 b = *(const bfv8*)&Bs[(nt*16+lm)*40 + lq*8];
        fv4 s = __builtin_amdgcn_mfma_f32_16x16x32_bf16(a, b, zz, 0,0,0);
        int col = nt*16+lm;
        int jj = kc*32 + (col&31);
        float u1v = u1s[jj], u12v = u12s[jj];
        #pragma unroll
        for (int r=0;r<4;r++){
          int row = rb + r;
          float vT = (r<2) ? vA : vB;
          float cf;
          if (kc < q) cf = u12v;
          else {
            int T = q*32 + (row>>1);
            if (kc == q) cf = (jj<=T) ? u12v : ((jj==T+1) ? u1v : 0.f);
            else         cf = (jj==T+1) ? u1v : 0.f;
          }
          Fs[row*72+col] = f2bf(cf*vT*s[r]);
        }
      }
    }
    __syncthreads();
    #pragma unroll
    for (int r2=0;r2<2;r2++){
      bfv8 a = *(const bfv8*)&Fs[(w*16+lm)*72 + r2*32 + lq*8];
      #pragma unroll
      for (int nt=0;nt<4;nt++){
        bfv8 b = *(const bfv8*)&Xs[(nt*16+lm)*72 + r2*32 + lq*8];
        acc[nt] = __builtin_amdgcn_mfma_f32_16x16x32_bf16(a, b, acc[nt], 0,0,0);
      }
    }
    if (q == 3){
      #pragma unroll
      for (int r2=0;r2<2;r2++){
        bfv8 a = *(const bfv8*)&Xs[(w*16+lm)*72 + r2*32 + lq*8];
        #pragma unroll
        for (int nt2=0;nt2<2;nt2++){
          bfv8 b = *(const bfv8*)&Bsn[(nt2*16+lm)*72 + r2*32 + lq*8];
          acch[nt2] = __builtin_amdgcn_mfma_f32_16x16x32_bf16(a, b, acch[nt2], 0,0,0);
        }
      }
    }
    __syncthreads();
  }
  #pragma unroll
  for (int nt=0;nt<4;nt++){
    int p = nt*16+lm;
    #pragma unroll
    for (int r=0;r<4;r++){
      int row = w*16+lq*4+r;
      int T = q*32+(row>>1), r1 = row&1;
      ypr[((size_t)(l0+T)*16 + h)*128 + p*2+r1] = f2bf(acc[nt][r]);
    }
  }
  if (q == 3){
    #pragma unroll
    for (int nt2=0;nt2<2;nt2++){
      int n = nt2*16+lm;
      #pragma unroll
      for (int r=0;r<4;r++){
        int p = w*16+lq*4+r;
        hfin[(((size_t)c*16+h)*64 + p)*32 + n] = f2bf(acch[nt2][r]);
      }
    }
    if (tid == 0) dcb[c*16+h] = __expf(cs_l[127]);
  }
  if (q == 0 && h4 == 0 && tid < 128) csb[(c*4+g)*128 + tid] = cs_l[tid];
}

// ------- K8AF: fused inter-chunk scan + y_off (MFMA) + ydown (MFMA) + gates, per (c,h) ---------
__global__ void __launch_bounds__(256) k8af(
  const bf16* __restrict__ Cr, const bf16* __restrict__ hfin,
  const float* __restrict__ dcb, const float* __restrict__ csb,
  bf16* __restrict__ ypr, const bf16* __restrict__ WydT,
  const bf16* __restrict__ proj, const float* __restrict__ Dp)
{
  __shared__ __align__(16) char arena[52224];
  bf16* C2s = (bf16*)arena;              // [256*40] 20480 B (phase 1)
  bf16* hT  = (bf16*)(arena + 20480);    // [64*40]   5120 B (phase 1)
  float* cse = (float*)(arena + 25600);  // [128]      512 B (phase 1)
  bf16* Yf  = (bf16*)arena;              // [128*136] 34816 B (phase 2, aliases C2s/hT/cse)
  bf16* Wds = (bf16*)(arena + 34816);    // [64*136] 17408 B (both phases)
  int h = blockIdx.x, c = blockIdx.y;
  int g = h >> 2;
  int tid = threadIdx.x;
  int l0 = c*TCH;
  int w = tid>>6, lane = tid&63, lm = lane&15, lq = lane>>4;
  for (int e4 = tid; e4 < 2048; e4 += 256){
    int tl = e4>>4, c4 = (e4&15)*4;
    bf4v v = *(const bf4v*)&Cr[((size_t)(l0+tl)*4+g)*64 + c4];
    bf16 arr[4] = {v.x,v.y,v.z,v.w};
    #pragma unroll
    for (int i=0;i<4;i++){ int q6=c4+i; C2s[((tl<<1)|(q6&1))*40 + (q6>>1)] = arr[i]; }
  }
  for (int e = tid; e < 1024; e += 256){
    int qq = e>>4, k8 = (e&15)*8;
    *(bf8s*)&Wds[qq*136 + k8] = *(const bf8s*)&WydT[qq*128 + k8];
  }
  {
    int e0 = tid*8;
    float carry[8] = {};
    for (int j = 0; j < c; j++){
      float dc = dcb[j*16+h];
      float4 a = ldb4(&hfin[((size_t)j*16+h)*2048 + e0]);
      float4 b = ldb4(&hfin[((size_t)j*16+h)*2048 + e0 + 4]);
      carry[0]=carry[0]*dc+a.x; carry[1]=carry[1]*dc+a.y; carry[2]=carry[2]*dc+a.z; carry[3]=carry[3]*dc+a.w;
      carry[4]=carry[4]*dc+b.x; carry[5]=carry[5]*dc+b.y; carry[6]=carry[6]*dc+b.z; carry[7]=carry[7]*dc+b.w;
    }
    int p = e0>>5, n = e0&31;
    stb4(&hT[p*40+n],   make_float4(carry[0],carry[1],carry[2],carry[3]));
    stb4(&hT[p*40+n+4], make_float4(carry[4],carry[5],carry[6],carry[7]));
  }
  if (tid < 128) cse[tid] = __expf(csb[(c*4+g)*128 + tid]);
  __syncthreads();
  float yfull[4][4][4];
  fv4 zz = {0.f,0.f,0.f,0.f};
  #pragma unroll
  for (int mi=0;mi<4;mi++){
    int mt = w*4 + mi;
    bfv8 a = *(const bfv8*)&C2s[(mt*16+lm)*40 + lq*8];
    #pragma unroll
    for (int nt=0;nt<4;nt++){
      bfv8 b = *(const bfv8*)&hT[(nt*16+lm)*40 + lq*8];
      fv4 s = __builtin_amdgcn_mfma_f32_16x16x32_bf16(a, b, zz, 0,0,0);
      int p = nt*16+lm;
      #pragma unroll
      for (int r=0;r<4;r++){
        int row = mt*16+lq*4+r;
        int tl = row>>1, r1 = row&1;
        float yd = bf2f(ypr[((size_t)(l0+tl)*16 + h)*128 + p*2 + r1]);
        yfull[mi][nt][r] = yd + cse[tl]*s[r];
      }
    }
  }
  __syncthreads();
  #pragma unroll
  for (int mi=0;mi<4;mi++){
    int mt = w*4 + mi;
    #pragma unroll
    for (int nt=0;nt<4;nt++){
      int p = nt*16+lm;
      #pragma unroll
      for (int r=0;r<4;r++){
        int row = mt*16+lq*4+r;
        int tl = row>>1, r1 = row&1;
        Yf[tl*136 + p*2 + r1] = f2bf(yfull[mi][nt][r]);
      }
    }
  }
  __syncthreads();
  fv4 acc2[2][4] = {};
  #pragma unroll
  for (int kq=0;kq<4;kq++){
    #pragma unroll
    for (int m2=0;m2<2;m2++){
      bfv8 a = *(const bfv8*)&Yf[((w*2+m2)*16+lm)*136 + kq*32 + lq*8];
      #pragma unroll
      for (int nt2=0;nt2<4;nt2++){
        bfv8 b = *(const bfv8*)&Wds[(nt2*16+lm)*136 + kq*32 + lq*8];
        acc2[m2][nt2] = __builtin_amdgcn_mfma_f32_16x16x32_bf16(a, b, acc2[m2][nt2], 0,0,0);
      }
    }
  }
  float dv = Dp[h];
  #pragma unroll
  for (int m2=0;m2<2;m2++){
    #pragma unroll
    for (int nt2=0;nt2<4;nt2++){
      int qq = nt2*16+lm;
      #pragma unroll
      for (int r=0;r<4;r++){
        int tl = (w*2+m2)*16 + lq*4 + r;
        size_t lrow = (size_t)(l0+tl)*DPROJ;
        float x = bf2f(proj[lrow + 1024 + h*64 + qq]);
        float z = bf2f(proj[lrow + h*64 + qq]);
        float xs = x/(1.f+__expf(-x));
        float zs = z/(1.f+__expf(-z));
        float outv = (acc2[m2][nt2][r] + dv*xs)*zs;
        ypr[((size_t)(l0+tl)*16 + h)*128 + 64 + qq] = f2bf(outv);
      }
    }
  }
}

extern "C" void kernel_launch(void* const* d_in, const int* in_sizes, int n_in,
                              void* d_out, int out_size, void* d_ws, size_t ws_size,
                              hipStream_t stream) {
  const float* u       = (const float*)d_in[0];
  const float* W_in    = (const float*)d_in[1];
  const float* b_in    = (const float*)d_in[2];
  const float* W_xup   = (const float*)d_in[3];
  const float* W_ydown = (const float*)d_in[4];
  const float* A_log   = (const float*)d_in[5];
  const float* theta_l = (const float*)d_in[6];
  const float* D_p     = (const float*)d_in[7];
  const float* wB      = (const float*)d_in[8];
  const float* wC      = (const float*)d_in[9];
  const float* biasB   = (const float*)d_in[10];
  const float* biasC   = (const float*)d_in[11];
  const float* W_out   = (const float*)d_in[12];
  float* out = (float*)d_out;

  char* w = (char*)d_ws;
  bf16*  proj  = (bf16*)(w);                       // 10,518,528 B
  float* dlraw = (float*)(w + 10518528);           //     65,536 B
  float* dtb   = (float*)(w + 10584064);           //     32,768 B
  float* lamb  = (float*)(w + 10616832);           //     32,768 B
  float* csdt  = (float*)(w + 10649600);           //     32,768 B
  bf16*  Brb   = (bf16*)(w + 10682368);            //  1,048,576 B
  bf16*  Crb   = (bf16*)(w + 11730944);            //  1,048,576 B
  bf16*  xupb  = (bf16*)(w + 12779520);            //  8,388,608 B
  bf16*  hfin  = (bf16*)(w + 21168128);            //  1,048,576 B
  float* dcb   = (float*)(w + 23265280);           //      1,024 B
  float* csb   = (float*)(w + 23266304);           //     32,768 B
  bf16*  ypr   = (bf16*)(w + 23299072);            //  8,388,608 B
  bf16*  WinT  = (bf16*)(w + 23299072);            //  aliased over ypr (dead once k6y writes ypr)
  bf16*  ubf   = (bf16*)(w + 31687680);            //  2,097,152 B
  bf16*  WoutT = (bf16*)(w + 33784832);            //  1,048,576 B
  bf16*  WydT  = (bf16*)(w + 34833408);            //     16,384 B

  prep<<<2888,256,0,stream>>>(u, ubf, W_in, WinT, W_out, WoutT, W_ydown, WydT);
  gemm1_mfma<<<dim3(21,16),256,0,stream>>>(ubf, WinT, b_in, proj, dlraw);
  k23<<<1,256,0,stream>>>(dlraw, dtb, lamb, csdt);
  k45<<<2048,256,0,stream>>>(proj, wB, wC, biasB, biasC, theta_l, csdt, W_xup, Brb, Crb, xupb);
  k6y<<<dim3(16,16,4),256,0,stream>>>(Brb, Crb, xupb, dtb, lamb, A_log, ypr, hfin, dcb, csb);
  k8af<<<dim3(16,16),256,0,stream>>>(Crb, hfin, dcb, csb, ypr, WydT, proj, D_p);
  gemmo_mfma<<<dim3(8,32),256,0,stream>>>(ypr, WoutT, out);
}